// Round 9
// baseline (370.558 us; speedup 1.0000x reference)
//
#include <hip/hip_runtime.h>
#include <hip/hip_bf16.h>

#define BB 64
#define SS 128
#define FF 16
#define HH 64
#define G4 256   // 4H
#define G3 192   // 3H

typedef unsigned short ushort_t;
typedef _Float16 f16_t;
typedef f16_t h2 __attribute__((ext_vector_type(2)));
typedef f16_t v8h __attribute__((ext_vector_type(8)));
typedef float v4f __attribute__((ext_vector_type(4)));

static __device__ __forceinline__ float rcpf(float x){
#if __has_builtin(__builtin_amdgcn_rcpf)
    return __builtin_amdgcn_rcpf(x);
#else
    return 1.0f/x;
#endif
}
static __device__ __forceinline__ float sigm(float x){ return rcpf(1.0f + __expf(-x)); }
static __device__ __forceinline__ float tanhfast(float x){ return 2.0f*rcpf(1.0f + __expf(-2.0f*x)) - 1.0f; }
static __device__ __forceinline__ h2 u2h(unsigned u){ return __builtin_bit_cast(h2, u); }
static __device__ __forceinline__ ushort_t f2h(float f){ f16_t h=(f16_t)f; return __builtin_bit_cast(ushort_t, h); }
static __device__ __forceinline__ float h2f(ushort_t u){ return (float)__builtin_bit_cast(f16_t, u); }
static __device__ __forceinline__ float dot2(h2 a, h2 b, float c){
#if __has_builtin(__builtin_amdgcn_fdot2)
    return __builtin_amdgcn_fdot2(a, b, c, false);
#else
    return fmaf((float)a.x,(float)b.x, fmaf((float)a.y,(float)b.y, c));
#endif
}

template<int C>
static __device__ __forceinline__ float dppf(float v){
    return __builtin_bit_cast(float,
        __builtin_amdgcn_update_dpp(0, __builtin_bit_cast(int, v), C, 0xf, 0xf, true));
}
// 16-lane butterfly reduce; result replicated to all 16 lanes of each group.
static __device__ __forceinline__ float wred16_max(float v){
    v = fmaxf(v, dppf<0xB1>(v));
    v = fmaxf(v, dppf<0x4E>(v));
    v = fmaxf(v, dppf<0x141>(v));
    v = fmaxf(v, dppf<0x140>(v));
    return v;
}
static __device__ __forceinline__ float wred16_sum(float v){
    v += dppf<0xB1>(v);
    v += dppf<0x4E>(v);
    v += dppf<0x141>(v);
    v += dppf<0x140>(v);
    return v;
}

static __device__ __forceinline__ void ldrow64(const float* p, size_t i, float* w){
    const float4* r = (const float4*)(p + i);
    #pragma unroll
    for (int j=0;j<16;j++){ float4 t=r[j]; w[4*j]=t.x; w[4*j+1]=t.y; w[4*j+2]=t.z; w[4*j+3]=t.w; }
}
// convert 8 consecutive f32 -> v8h (for MFMA B-fragments from global weights)
static __device__ __forceinline__ v8h cvt8(const float* p){
    float4 a = ((const float4*)p)[0];
    float4 b = ((const float4*)p)[1];
    v8h v;
    v[0]=(f16_t)a.x; v[1]=(f16_t)a.y; v[2]=(f16_t)a.z; v[3]=(f16_t)a.w;
    v[4]=(f16_t)b.x; v[5]=(f16_t)b.y; v[6]=(f16_t)b.z; v[7]=(f16_t)b.w;
    return v;
}

// raw per-step sync: commit own LDS writes, barrier. NO vmcnt drain -> the
// flush's global stores stay in flight across steps (T4 pattern, m201).
static __device__ __forceinline__ void step_sync(){
    __builtin_amdgcn_sched_barrier(0);
    asm volatile("s_waitcnt lgkmcnt(0)" ::: "memory");
    __builtin_amdgcn_s_barrier();
    __builtin_amdgcn_sched_barrier(0);
}
// intra-wave LDS drain (no barrier): order own ds_write -> ds_read.
static __device__ __forceinline__ void lds_drain(){
    __builtin_amdgcn_sched_barrier(0);
    asm volatile("s_waitcnt lgkmcnt(0)" ::: "memory");
    __builtin_amdgcn_sched_barrier(0);
}

__global__ void sig_kernel(float* dout, int n, float val){
    int i = blockIdx.x*256 + threadIdx.x;
    if (i < n) dout[i] = val;
}

// ---------------------------------------------------------------------------
// init: static/time MLPs + fc bias -> accb (fp32, in d_ws); liveness magic.
// ---------------------------------------------------------------------------
__global__ __launch_bounds__(64) void init_kernel(
    const float* __restrict__ stat, const float* __restrict__ tg,
    const float* __restrict__ d1w, const float* __restrict__ d1b,
    const float* __restrict__ d2w, const float* __restrict__ d2b,
    const float* __restrict__ t1w, const float* __restrict__ t1b,
    const float* __restrict__ t2w, const float* __restrict__ t2b,
    const float* __restrict__ fcw, const float* __restrict__ fcb,
    float* __restrict__ accb)
{
    const int b = threadIdx.x;
    float sr[32];
    for (int k=0;k<32;++k) sr[k] = stat[(size_t)b*32 + k];
    float h1[64];
    for (int j=0;j<64;++j){
        float a = d1b[j];
        for (int k=0;k<32;++k) a = fmaf(sr[k], d1w[(size_t)j*32+k], a);
        h1[j] = fmaxf(a, 0.0f);
    }
    float sf[32];
    for (int i=0;i<32;++i){
        float a = d2b[i];
        for (int j=0;j<64;++j) a = fmaf(h1[j], d2w[(size_t)i*64+j], a);
        sf[i] = fmaxf(a, 0.0f);
    }
    float tgv = tg[b];
    float th[16];
    for (int j=0;j<16;++j) th[j] = fmaxf(fmaf(tgv, t1w[j], t1b[j]), 0.0f);
    float tf[8];
    for (int i=0;i<8;++i){
        float a = t2b[i];
        for (int j=0;j<16;++j) a = fmaf(th[j], t2w[(size_t)i*16+j], a);
        tf[i] = fmaxf(a, 0.0f);
    }
    float o0 = fcb[0], o1 = fcb[1];
    for (int i=0;i<32;++i){
        o0 = fmaf(sf[i], fcw[2048+i],      o0);
        o1 = fmaf(sf[i], fcw[2088+2048+i], o1);
    }
    for (int i=0;i<8;++i){
        o0 = fmaf(tf[i], fcw[2080+i],      o0);
        o1 = fmaf(tf[i], fcw[2088+2080+i], o1);
    }
    accb[2*b]   = o0;
    accb[2*b+1] = o1;
    if (b == 0) accb[128] = 123.0f;
}

// ---------------------------------------------------------------------------
// lstm_kernel (R13, kept): batched-b MFMA LSTM with 8-step group unroll.
// ---------------------------------------------------------------------------
__global__ __launch_bounds__(256) void lstm_kernel(
    const float* __restrict__ wd_x, const float* __restrict__ rd_x,
    const float* __restrict__ wd_Wih, const float* __restrict__ wd_Whh,
    const float* __restrict__ wd_bih, const float* __restrict__ wd_bhh,
    const float* __restrict__ rd_Wih, const float* __restrict__ rd_Whh,
    const float* __restrict__ rd_bih, const float* __restrict__ rd_bhh,
    float* __restrict__ dout)
{
    const int bid = blockIdx.x;            // 128 blocks
    const int branch = bid >> 6;
    const int f = (bid >> 2) & 15;
    const int q = bid & 3;                 // batch quarter: b = q*16 + m
    const float* xin = branch ? rd_x   : wd_x;
    const float* Wih = branch ? rd_Wih : wd_Wih;
    const float* Whh = branch ? rd_Whh : wd_Whh;
    const float* bih = branch ? rd_bih : wd_bih;
    const float* bhh = branch ? rd_bhh : wd_bhh;

    __shared__ __align__(16) float xseq[SS][16];          // 8 KB  [s][m]
    __shared__ __align__(16) ushort_t stg2[2][16][8][64]; // 32 KB dbuf history

    const int tid  = threadIdx.x;
    const int w    = tid >> 6;
    const int lane = tid & 63;
    const int quad = lane >> 4;
    const int ln   = lane & 15;

    // B-frags (Whh rows as f16), wih, bias for tiles {w, w+4, w+8, w+12}
    v8h bfr[4][2];
    float wihv[4], bsv[4];
    #pragma unroll
    for (int i=0;i<4;++i){
        const int gate = (w + 4*i)*16 + ln;
        wihv[i] = Wih[f*G4 + gate];
        bsv[i]  = bih[f*G4 + gate] + bhh[f*G4 + gate];
        #pragma unroll
        for (int Ks=0;Ks<2;++Ks){
            const float* wr = Whh + ((size_t)f*G4 + gate)*HH + Ks*32 + quad*8;
            float4 aa = ((const float4*)wr)[0];
            float4 bb = ((const float4*)wr)[1];
            v8h v;
            v[0]=(f16_t)aa.x; v[1]=(f16_t)aa.y; v[2]=(f16_t)aa.z; v[3]=(f16_t)aa.w;
            v[4]=(f16_t)bb.x; v[5]=(f16_t)bb.y; v[6]=(f16_t)bb.z; v[7]=(f16_t)bb.w;
            bfr[i][Ks] = v;
        }
    }
    // xseq load: x[b][s][f] -> [s][m]
    #pragma unroll
    for (int j=0;j<8;++j){
        int e = tid + 256*j;               // 0..2047
        int s = e >> 4, m = e & 15;
        xseq[s][m] = xin[((size_t)(q*16+m)*SS + s)*FF + f];
    }
    { // zero the h(-1) slot: stg2[1][m][7][*]  (read by step s=0)
        #pragma unroll
        for (int jz=0;jz<2;++jz){
            int d = tid + 256*jz;          // 0..511 dwords
            int m = d >> 5, c = d & 31;
            *(unsigned*)(&stg2[1][m][7][c*2]) = 0u;
        }
    }
    float c0=0.f, c1=0.f, c2=0.f, c3=0.f;
    __syncthreads();

    ushort_t* const sb = &stg2[0][0][0][0];
    const int physA0 = ((0*4 + quad) ^ (ln & 7)) * 8;  // A-frag col (Ks=0)
    const int physA1 = ((1*4 + quad) ^ (ln & 7)) * 8;  // A-frag col (Ks=1)
    const int arow   = ln*512;                         // this lane's A row (m=ln)
    const int hmy  = w*16 + ln;                        // this lane's h index
    const int hblk = hmy >> 3, hlow = hmy & 7;
    int woff[4];                                       // h-write offsets per r
    #pragma unroll
    for (int r=0;r<4;++r){
        const int m = quad*4 + r;
        woff[r] = m*512 + (((hblk ^ (m&7))<<3) | hlow);
    }
    // flush constants: thread (cm,part) stores uint4 g=part+16*jj of its cell.
    const int cm = tid >> 4, part = tid & 15;
    float* const flbase = dout + 128
        + (size_t)(branch*1024 + f*64 + (q*16 + cm)) * 16384;
    int fsrc[4], fg[4];
    #pragma unroll
    for (int jj=0;jj<4;++jj){
        const int g = part + 16*jj;
        fg[jj]   = g;
        fsrc[jj] = cm*64 + (g>>3)*8 + ((g&7) ^ (cm&7));
    }

    // step-0 C-init precompute
    float4 xv = *(const float4*)&xseq[0][quad*4];
    v4f cip[4];
    #pragma unroll
    for (int i=0;i<4;++i){
        v4f ci;
        ci[0] = fmaf(xv.x, wihv[i], bsv[i]);
        ci[1] = fmaf(xv.y, wihv[i], bsv[i]);
        ci[2] = fmaf(xv.z, wihv[i], bsv[i]);
        ci[3] = fmaf(xv.w, wihv[i], bsv[i]);
        cip[i] = ci;
    }

    #pragma unroll 1
    for (int g8=0; g8<16; ++g8){
        const int wb = g8 & 1;
        ushort_t* const wbp = sb + wb*8192;
        const ushort_t* const pbp = sb + (wb^1)*8192;
        #pragma unroll
        for (int k=0;k<8;++k){
            const int s = g8*8 + k;
            const ushort_t* ap = (k==0) ? (pbp + arow + 7*64)
                                        : (wbp + arow + (k-1)*64);
            v8h a0 = *(const v8h*)(ap + physA0);       // A[m=ln][k=quad*8+j]
            v8h a1 = *(const v8h*)(ap + physA1);

            // prefetch next xv (static data; off next step's critical chain)
            const int sn = (s < SS-1) ? s+1 : s;
            float4 xvn = *(const float4*)&xseq[sn][quad*4];

            v4f acc[4];
            #pragma unroll
            for (int i=0;i<4;++i){
                v4f t = __builtin_amdgcn_mfma_f32_16x16x32_f16(a0, bfr[i][0], cip[i], 0,0,0);
                acc[i] = __builtin_amdgcn_mfma_f32_16x16x32_f16(a1, bfr[i][1], t, 0,0,0);
            }
            // next-step C-init (VALU, overlaps MFMA)
            #pragma unroll
            for (int i=0;i<4;++i){
                v4f ci;
                ci[0] = fmaf(xvn.x, wihv[i], bsv[i]);
                ci[1] = fmaf(xvn.y, wihv[i], bsv[i]);
                ci[2] = fmaf(xvn.z, wihv[i], bsv[i]);
                ci[3] = fmaf(xvn.w, wihv[i], bsv[i]);
                cip[i] = ci;
            }

            // D layout: row m = quad*4+r, col = ln. acc[0..3]=i,f,g,o for h=hmy.
            ushort_t* wp = wbp + k*64;
            #pragma unroll
            for (int r=0;r<4;++r){
                float iv = sigm(acc[0][r]);
                float fv = sigm(acc[1][r]);
                float gv = tanhfast(acc[2][r]);
                float ov = sigm(acc[3][r]);
                float& cc = (r==0)?c0:(r==1)?c1:(r==2)?c2:c3;
                cc = fmaf(fv, cc, iv*gv);
                float hv = ov * tanhfast(cc);
                wp[woff[r]] = f2h(hv);
            }
            step_sync();
        }
        { // coalesced flush of this 8-step group
            const uint4* src4 = (const uint4*)wbp;
            uint4* dst4 = (uint4*)(flbase + (size_t)(g8*8)*32);
            #pragma unroll
            for (int jj=0;jj<4;++jj)
                dst4[fg[jj]] = src4[fsrc[jj]];
        }
    }
}

// ---------------------------------------------------------------------------
// attn_kernel (R18 = R17 with LDS 44->40 KB): R10 4-wave skeleton +
//  - V-in-registers (vacc); PV tail from registers.
//  - Full-line staged attn-weight stores (regular, cache-resident).
//  - R18 change: the 4 KB S scratch is merged into stS (8 KB = 2048 floats,
//    time-disjoint uses separated by barriers):
//      phase2: stS[wave][512] store staging (per-wave, intra-wave drain)
//      tail:   Sf[0..1023] colsum stash -> rsum (in place),
//              Sf[1024..1279] PV partials, Sf[1280..1343] o_mean.
//    LDS 40960 -> 4 blocks/CU (was 2 resident at 44 KB). launch_bounds(256,4).
// ---------------------------------------------------------------------------
__global__ __launch_bounds__(256, 4) void attn_kernel(
    const float* __restrict__ wd_aw, const float* __restrict__ wd_ab,
    const float* __restrict__ wd_ow, const float* __restrict__ wd_ob,
    const float* __restrict__ rd_aw, const float* __restrict__ rd_ab,
    const float* __restrict__ rd_ow, const float* __restrict__ rd_ob,
    const float* __restrict__ fcw,
    float* __restrict__ dout, float* __restrict__ accb)
{
    const int bid = blockIdx.x;
    const int branch = bid >> 10;
    const int b = (bid >> 4) & 63;
    const int f = bid & 15;
    const float* aw = branch ? rd_aw : wd_aw;
    const float* ab = branch ? rd_ab : wd_ab;
    const float* ow = branch ? rd_ow : wd_ow;
    const float* ob = branch ? rd_ob : wd_ob;

    const size_t cell = (size_t)branch*1024 + (size_t)f*64 + b;
    float* slot = dout + 128 + cell*16384;

    __shared__ __align__(16) ushort_t xb[SS][64];   // staged x, then q (swizzled)
    __shared__ __align__(16) ushort_t kb[SS][64];   // k, XOR-swizzled rows
    __shared__ __align__(16) float stS[4][512];     // store stage + tail scratch

    float* Sf = &stS[0][0];                          // flat 2048-float view
    const int tid  = threadIdx.x;
    const int wave = tid >> 6;
    const int lane = tid & 63;
    const int quad = lane >> 4;
    const int ln   = lane & 15;

    { // staged x -> LDS (16 KB) with XOR block swizzle: blk' = blk ^ (s&7)
        const uint4* src = (const uint4*)slot;
        uint4* dst = (uint4*)&xb[0][0];
        #pragma unroll
        for (int j=0;j<4;++j){
            const int g = tid + 256*j;            // uint4 index 0..1023
            const int s = g >> 3, blk = g & 7;
            dst[s*8 + (blk ^ (s&7))] = src[g];
        }
    }
    __syncthreads();

    // ---- phase 1: projections via MFMA. Wave owns M-tiles {2w, 2w+1}. ----
    v8h ax[2][2];   // A-frags of x: [mt][Ks], row = mt*16+ln, k = Ks*32+quad*8+j
    #pragma unroll
    for (int mt=0;mt<2;++mt){
        const int row = (wave*2+mt)*16 + ln;
        #pragma unroll
        for (int Ks=0;Ks<2;++Ks){
            const int blk = Ks*4 + quad;
            ax[mt][Ks] = *(const v8h*)((const char*)&xb[0][0]
                          + row*128 + ((blk ^ (row&7))<<4));
        }
    }
    const float* awf = aw + (size_t)f*G3*HH;
    const float* abf = ab + (size_t)f*G3;

    // K projection -> kb (swizzled)
    #pragma unroll
    for (int nt=0;nt<4;++nt){
        const int g = nt*16 + ln;                 // output channel (B col n)
        const float* wr = awf + (size_t)(HH + g)*HH + quad*8;
        v8h b0 = cvt8(wr);
        v8h b1 = cvt8(wr + 32);
        const float bias = abf[HH + g];
        #pragma unroll
        for (int mt=0;mt<2;++mt){
            v4f ci; ci[0]=bias; ci[1]=bias; ci[2]=bias; ci[3]=bias;
            ci = __builtin_amdgcn_mfma_f32_16x16x32_f16(ax[mt][0], b0, ci, 0,0,0);
            ci = __builtin_amdgcn_mfma_f32_16x16x32_f16(ax[mt][1], b1, ci, 0,0,0);
            #pragma unroll
            for (int r=0;r<4;++r){
                const int s = (wave*2+mt)*16 + quad*4 + r;
                kb[s][ (((g>>3) ^ (s&7))<<3) | (g&7) ] = f2h(ci[r]);
            }
        }
    }
    // V projection -> vacc registers (D-layout: row=(2w+mt)*16+quad*4+r,
    // col=nt*16+ln). NO LDS staging — consumed by the register PV tail.
    v4f vacc[2][4];
    #pragma unroll
    for (int nt=0;nt<4;++nt){
        const int g = nt*16 + ln;
        const float* wr = awf + (size_t)(2*HH + g)*HH + quad*8;
        v8h b0 = cvt8(wr);
        v8h b1 = cvt8(wr + 32);
        const float bias = abf[2*HH + g];
        #pragma unroll
        for (int mt=0;mt<2;++mt){
            v4f ci; ci[0]=bias; ci[1]=bias; ci[2]=bias; ci[3]=bias;
            ci = __builtin_amdgcn_mfma_f32_16x16x32_f16(ax[mt][0], b0, ci, 0,0,0);
            vacc[mt][nt] = __builtin_amdgcn_mfma_f32_16x16x32_f16(ax[mt][1], b1, ci, 0,0,0);
        }
    }
    // Q projection -> regs (x LDS reads by other waves complete before barrier)
    v4f qacc[2][4];
    #pragma unroll
    for (int nt=0;nt<4;++nt){
        const int g = nt*16 + ln;
        const float* wr = awf + (size_t)g*HH + quad*8;
        v8h b0 = cvt8(wr);
        v8h b1 = cvt8(wr + 32);
        const float bias = abf[g];
        #pragma unroll
        for (int mt=0;mt<2;++mt){
            v4f ci; ci[0]=bias; ci[1]=bias; ci[2]=bias; ci[3]=bias;
            ci = __builtin_amdgcn_mfma_f32_16x16x32_f16(ax[mt][0], b0, ci, 0,0,0);
            qacc[mt][nt] = __builtin_amdgcn_mfma_f32_16x16x32_f16(ax[mt][1], b1, ci, 0,0,0);
        }
    }
    __syncthreads();   // all x reads complete -> safe to overwrite xb with q
    #pragma unroll
    for (int mt=0;mt<2;++mt){
        #pragma unroll
        for (int nt=0;nt<4;++nt){
            #pragma unroll
            for (int r=0;r<4;++r){
                const int s = (wave*2+mt)*16 + quad*4 + r;
                const int g = nt*16 + ln;
                xb[s][ (((g>>3) ^ (s&7))<<3) | (g&7) ] =
                    f2h(qacc[mt][nt][r] * 0.17677669529663687f);
            }
        }
    }
    __syncthreads();

    // ---- phase 2: scores via MFMA (per head K=32), DPP softmax, writes ----
    float cs[8][2];                    // colsum accum: [nt][head], t = nt*16+ln
    #pragma unroll
    for (int i=0;i<8;++i){ cs[i][0]=0.f; cs[i][1]=0.f; }

    #pragma unroll
    for (int mt=0;mt<2;++mt){
        const int mrow = (wave*2+mt)*16;
        v8h aq[2];                     // q A-frags per head: k = h*32+quad*8+j
        #pragma unroll
        for (int h=0;h<2;++h){
            const int row = mrow + ln;
            const int blk = h*4 + quad;
            aq[h] = *(const v8h*)((const char*)&xb[0][0]
                      + row*128 + ((blk ^ (row&7))<<4));
        }
        v4f sc[8][2];
        #pragma unroll
        for (int nt=0;nt<8;++nt){
            const int trow = nt*16 + ln;
            #pragma unroll
            for (int h=0;h<2;++h){
                const int blk = h*4 + quad;
                v8h bk = *(const v8h*)((const char*)&kb[0][0]
                           + trow*128 + ((blk ^ (trow&7))<<4));
                v4f z; z[0]=0.f; z[1]=0.f; z[2]=0.f; z[3]=0.f;
                sc[nt][h] = __builtin_amdgcn_mfma_f32_16x16x32_f16(aq[h], bk, z, 0,0,0);
            }
        }
        // softmax: row s1 = mrow + quad*4 + r spans lanes of this quad x 8 nt
        #pragma unroll
        for (int r=0;r<4;++r){
            #pragma unroll
            for (int h=0;h<2;++h){
                float m = sc[0][h][r];
                #pragma unroll
                for (int nt=1;nt<8;++nt) m = fmaxf(m, sc[nt][h][r]);
                m = wred16_max(m);
                float e0=__expf(sc[0][h][r]-m), e1=__expf(sc[1][h][r]-m);
                float e2=__expf(sc[2][h][r]-m), e3=__expf(sc[3][h][r]-m);
                float e4=__expf(sc[4][h][r]-m), e5=__expf(sc[5][h][r]-m);
                float e6=__expf(sc[6][h][r]-m), e7=__expf(sc[7][h][r]-m);
                float ssum = ((e0+e1)+(e2+e3)) + ((e4+e5)+(e6+e7));
                ssum = wred16_sum(ssum);
                const float inv = rcpf(ssum);
                sc[0][h][r]=e0*inv; sc[1][h][r]=e1*inv;
                sc[2][h][r]=e2*inv; sc[3][h][r]=e3*inv;
                sc[4][h][r]=e4*inv; sc[5][h][r]=e5*inv;
                sc[6][h][r]=e6*inv; sc[7][h][r]=e7*inv;
                #pragma unroll
                for (int nt=0;nt<8;++nt) cs[nt][h] += sc[nt][h][r];
            }
            // store-stage: each quad deposits its row r (t = nt*16+ln)
            #pragma unroll
            for (int nt=0;nt<8;++nt)
                stS[wave][quad*128 + nt*16 + ln] = 0.5f*(sc[nt][0][r] + sc[nt][1][r]);
            lds_drain();   // intra-wave: own region, no cross-wave barrier
            {
                const int qs = lane >> 5;             // 0/1: quad-pair select
                const int il = lane & 31;
                v4f v0 = *(const v4f*)&stS[wave][ qs   *128 + il*4];
                v4f v1 = *(const v4f*)&stS[wave][(qs+2)*128 + il*4];
                // lanes 0-31: full row (mrow+qs*4+r); lanes 32-63: row (+8).
                *(v4f*)(slot + (size_t)(mrow + qs*4 + r)*SS + il*4) = v0;
                *(v4f*)(slot + (size_t)(mrow + (qs+2)*4 + r)*SS + il*4) = v1;
            }
        }
    }

    // reduce colsums across quads (rows of this wave), stash per-wave to LDS
    #pragma unroll
    for (int nt=0;nt<8;++nt){
        #pragma unroll
        for (int h=0;h<2;++h){
            float v = cs[nt][h];
            v += __shfl_xor(v, 16);
            v += __shfl_xor(v, 32);
            cs[nt][h] = v;
        }
    }
    __syncthreads();   // phase-2 stS reads done block-wide before tail reuse
    if (lane < 16){
        #pragma unroll
        for (int nt=0;nt<8;++nt){
            Sf[wave*256 +       nt*16 + lane] = cs[nt][0];
            Sf[wave*256 + 128 + nt*16 + lane] = cs[nt][1];
        }
    }
    __syncthreads();

    {
        float rsum = (Sf[tid] + Sf[256+tid] + Sf[512+tid] + Sf[768+tid]) * (1.0f/128.0f);
        Sf[tid] = rsum;                                // own-read position only
    }
    __syncthreads();

    {   // PV from registers: partial[h=nt*16+ln] over this wave's 32 V rows.
        // rsum[t] read as quad-uniform broadcast; head slice = nt>>1.
        float part[4];
        #pragma unroll
        for (int nt=0;nt<4;++nt){
            const float* rr = &Sf[(nt>>1)*128];
            float p = 0.f;
            #pragma unroll
            for (int mt=0;mt<2;++mt){
                const int t0 = (wave*2+mt)*16 + quad*4;
                #pragma unroll
                for (int r=0;r<4;++r)
                    p = fmaf(rr[t0+r], vacc[mt][nt][r], p);
            }
            p += __shfl_xor(p, 16);
            p += __shfl_xor(p, 32);
            part[nt] = p;
        }
        if (lane < 16){
            #pragma unroll
            for (int nt=0;nt<4;++nt)
                Sf[1024 + wave*64 + nt*16 + lane] = part[nt];
        }
    }
    __syncthreads();
    if (tid < HH){
        Sf[1280+tid] = Sf[1024+tid] + Sf[1088+tid]
                     + Sf[1152+tid] + Sf[1216+tid];
    }
    __syncthreads();

    if (tid < HH){   // pooled = o_mean @ Wout^T + bout, then fc dot + atomic
        const int g = tid;
        float w2f[64];
        ldrow64(ow, ((size_t)f*HH + g)*HH, w2f);
        float pacc = ob[f*HH + g];
        const float4* om4 = (const float4*)&Sf[1280];
        #pragma unroll
        for (int j=0;j<16;j++){
            float4 o4 = om4[j];
            pacc = fmaf(w2f[4*j+0],o4.x,pacc); pacc = fmaf(w2f[4*j+1],o4.y,pacc);
            pacc = fmaf(w2f[4*j+2],o4.z,pacc); pacc = fmaf(w2f[4*j+3],o4.w,pacc);
        }
        const size_t ci = (size_t)branch*1024 + (size_t)f*64 + g;
        float c0 = pacc * fcw[ci];
        float c1 = pacc * fcw[2088 + ci];
        #pragma unroll
        for (int off=1; off<64; off<<=1){
            c0 += __shfl_xor(c0, off);
            c1 += __shfl_xor(c1, off);
        }
        if (tid == 0){
            atomicAdd(&accb[2*b],   c0);
            atomicAdd(&accb[2*b+1], c1);
        }
    }
}

// fin: fp32-store the accumulator into d_out[0:128].
__global__ __launch_bounds__(64) void fin_kernel(
    const float* __restrict__ accb, float* __restrict__ dout)
{
    const int t = threadIdx.x;
    float v0, v1;
    if (accb[128] != 123.0f){ v0 = 760.0f; v1 = 760.0f; }
    else { v0 = accb[2*t]; v1 = accb[2*t+1]; }
    dout[2*t]   = v0;
    dout[2*t+1] = v1;
}

extern "C" void kernel_launch(void* const* d_in, const int* in_sizes, int n_in,
                              void* d_out, int out_size, void* d_ws, size_t ws_size,
                              hipStream_t stream)
{
    static const int exp_sizes[30] = {
        131072,131072,2048,64,
        4096,262144,4096,4096,  4096,262144,4096,4096,
        196608,3072,65536,1024, 196608,3072,65536,1024,
        2048,64,2048,32, 16,16,128,8, 4176,2 };

    bool ok_sizes = (n_in == 30);
    if (ok_sizes) for (int i=0;i<30;++i) if (in_sizes[i] != exp_sizes[i]) { ok_sizes = false; break; }
    const bool ok_out = (out_size == 33554560);
    const bool ok_ws  = (ws_size >= 1024);

    if (!ok_sizes || !ok_out || !ok_ws){
        float sig = !ok_sizes ? 3000.0f : (!ok_out ? 5000.0f : 7000.0f);
        int n = out_size < 128 ? out_size : 128;
        sig_kernel<<<dim3(1), dim3(256), 0, stream>>>((float*)d_out, n, sig);
        return;
    }

    float* accb = (float*)((char*)d_ws + 64);
    float* out  = (float*)d_out;

    init_kernel<<<dim3(1), dim3(64), 0, stream>>>(
        (const float*)d_in[2], (const float*)d_in[3],
        (const float*)d_in[20], (const float*)d_in[21],
        (const float*)d_in[22], (const float*)d_in[23],
        (const float*)d_in[24], (const float*)d_in[25],
        (const float*)d_in[26], (const float*)d_in[27],
        (const float*)d_in[28], (const float*)d_in[29], accb);

    lstm_kernel<<<dim3(128), dim3(256), 0, stream>>>(
        (const float*)d_in[0], (const float*)d_in[1],
        (const float*)d_in[4], (const float*)d_in[5],
        (const float*)d_in[6], (const float*)d_in[7],
        (const float*)d_in[8], (const float*)d_in[9],
        (const float*)d_in[10], (const float*)d_in[11], out);

    attn_kernel<<<dim3(2048), dim3(256), 0, stream>>>(
        (const float*)d_in[12], (const float*)d_in[13],
        (const float*)d_in[14], (const float*)d_in[15],
        (const float*)d_in[16], (const float*)d_in[17],
        (const float*)d_in[18], (const float*)d_in[19],
        (const float*)d_in[28], out, accb);

    fin_kernel<<<dim3(1), dim3(64), 0, stream>>>(accb, out);
}

// Round 10
// 350.766 us; speedup vs baseline: 1.0564x; 1.0564x over previous
//
#include <hip/hip_runtime.h>
#include <hip/hip_bf16.h>

#define BB 64
#define SS 128
#define FF 16
#define HH 64
#define G4 256   // 4H
#define G3 192   // 3H

typedef unsigned short ushort_t;
typedef _Float16 f16_t;
typedef f16_t h2 __attribute__((ext_vector_type(2)));
typedef f16_t v8h __attribute__((ext_vector_type(8)));
typedef float v4f __attribute__((ext_vector_type(4)));

static __device__ __forceinline__ float rcpf(float x){
#if __has_builtin(__builtin_amdgcn_rcpf)
    return __builtin_amdgcn_rcpf(x);
#else
    return 1.0f/x;
#endif
}
static __device__ __forceinline__ float sigm(float x){ return rcpf(1.0f + __expf(-x)); }
static __device__ __forceinline__ float tanhfast(float x){ return 2.0f*rcpf(1.0f + __expf(-2.0f*x)) - 1.0f; }
static __device__ __forceinline__ h2 u2h(unsigned u){ return __builtin_bit_cast(h2, u); }
static __device__ __forceinline__ ushort_t f2h(float f){ f16_t h=(f16_t)f; return __builtin_bit_cast(ushort_t, h); }
static __device__ __forceinline__ float h2f(ushort_t u){ return (float)__builtin_bit_cast(f16_t, u); }
static __device__ __forceinline__ float dot2(h2 a, h2 b, float c){
#if __has_builtin(__builtin_amdgcn_fdot2)
    return __builtin_amdgcn_fdot2(a, b, c, false);
#else
    return fmaf((float)a.x,(float)b.x, fmaf((float)a.y,(float)b.y, c));
#endif
}

template<int C>
static __device__ __forceinline__ float dppf(float v){
    return __builtin_bit_cast(float,
        __builtin_amdgcn_update_dpp(0, __builtin_bit_cast(int, v), C, 0xf, 0xf, true));
}
// 16-lane butterfly reduce; result replicated to all 16 lanes of each group.
static __device__ __forceinline__ float wred16_max(float v){
    v = fmaxf(v, dppf<0xB1>(v));
    v = fmaxf(v, dppf<0x4E>(v));
    v = fmaxf(v, dppf<0x141>(v));
    v = fmaxf(v, dppf<0x140>(v));
    return v;
}
static __device__ __forceinline__ float wred16_sum(float v){
    v += dppf<0xB1>(v);
    v += dppf<0x4E>(v);
    v += dppf<0x141>(v);
    v += dppf<0x140>(v);
    return v;
}

static __device__ __forceinline__ void ldrow64(const float* p, size_t i, float* w){
    const float4* r = (const float4*)(p + i);
    #pragma unroll
    for (int j=0;j<16;j++){ float4 t=r[j]; w[4*j]=t.x; w[4*j+1]=t.y; w[4*j+2]=t.z; w[4*j+3]=t.w; }
}
// convert 8 consecutive f32 -> v8h (for MFMA B-fragments from global weights)
static __device__ __forceinline__ v8h cvt8(const float* p){
    float4 a = ((const float4*)p)[0];
    float4 b = ((const float4*)p)[1];
    v8h v;
    v[0]=(f16_t)a.x; v[1]=(f16_t)a.y; v[2]=(f16_t)a.z; v[3]=(f16_t)a.w;
    v[4]=(f16_t)b.x; v[5]=(f16_t)b.y; v[6]=(f16_t)b.z; v[7]=(f16_t)b.w;
    return v;
}

// raw per-step sync: commit own LDS writes, barrier. NO vmcnt drain -> the
// flush's global stores stay in flight across steps (T4 pattern, m201).
static __device__ __forceinline__ void step_sync(){
    __builtin_amdgcn_sched_barrier(0);
    asm volatile("s_waitcnt lgkmcnt(0)" ::: "memory");
    __builtin_amdgcn_s_barrier();
    __builtin_amdgcn_sched_barrier(0);
}
// intra-wave LDS drain (no barrier): order own ds_write -> ds_read.
static __device__ __forceinline__ void lds_drain(){
    __builtin_amdgcn_sched_barrier(0);
    asm volatile("s_waitcnt lgkmcnt(0)" ::: "memory");
    __builtin_amdgcn_sched_barrier(0);
}

__global__ void sig_kernel(float* dout, int n, float val){
    int i = blockIdx.x*256 + threadIdx.x;
    if (i < n) dout[i] = val;
}

// ---------------------------------------------------------------------------
// init: static/time MLPs + fc bias -> accb (fp32, in d_ws); liveness magic.
// ---------------------------------------------------------------------------
__global__ __launch_bounds__(64) void init_kernel(
    const float* __restrict__ stat, const float* __restrict__ tg,
    const float* __restrict__ d1w, const float* __restrict__ d1b,
    const float* __restrict__ d2w, const float* __restrict__ d2b,
    const float* __restrict__ t1w, const float* __restrict__ t1b,
    const float* __restrict__ t2w, const float* __restrict__ t2b,
    const float* __restrict__ fcw, const float* __restrict__ fcb,
    float* __restrict__ accb)
{
    const int b = threadIdx.x;
    float sr[32];
    for (int k=0;k<32;++k) sr[k] = stat[(size_t)b*32 + k];
    float h1[64];
    for (int j=0;j<64;++j){
        float a = d1b[j];
        for (int k=0;k<32;++k) a = fmaf(sr[k], d1w[(size_t)j*32+k], a);
        h1[j] = fmaxf(a, 0.0f);
    }
    float sf[32];
    for (int i=0;i<32;++i){
        float a = d2b[i];
        for (int j=0;j<64;++j) a = fmaf(h1[j], d2w[(size_t)i*64+j], a);
        sf[i] = fmaxf(a, 0.0f);
    }
    float tgv = tg[b];
    float th[16];
    for (int j=0;j<16;++j) th[j] = fmaxf(fmaf(tgv, t1w[j], t1b[j]), 0.0f);
    float tf[8];
    for (int i=0;i<8;++i){
        float a = t2b[i];
        for (int j=0;j<16;++j) a = fmaf(th[j], t2w[(size_t)i*16+j], a);
        tf[i] = fmaxf(a, 0.0f);
    }
    float o0 = fcb[0], o1 = fcb[1];
    for (int i=0;i<32;++i){
        o0 = fmaf(sf[i], fcw[2048+i],      o0);
        o1 = fmaf(sf[i], fcw[2088+2048+i], o1);
    }
    for (int i=0;i<8;++i){
        o0 = fmaf(tf[i], fcw[2080+i],      o0);
        o1 = fmaf(tf[i], fcw[2088+2080+i], o1);
    }
    accb[2*b]   = o0;
    accb[2*b+1] = o1;
    if (b == 0) accb[128] = 123.0f;
}

// ---------------------------------------------------------------------------
// lstm_kernel (R13, kept): batched-b MFMA LSTM with 8-step group unroll.
// ---------------------------------------------------------------------------
__global__ __launch_bounds__(256) void lstm_kernel(
    const float* __restrict__ wd_x, const float* __restrict__ rd_x,
    const float* __restrict__ wd_Wih, const float* __restrict__ wd_Whh,
    const float* __restrict__ wd_bih, const float* __restrict__ wd_bhh,
    const float* __restrict__ rd_Wih, const float* __restrict__ rd_Whh,
    const float* __restrict__ rd_bih, const float* __restrict__ rd_bhh,
    float* __restrict__ dout)
{
    const int bid = blockIdx.x;            // 128 blocks
    const int branch = bid >> 6;
    const int f = (bid >> 2) & 15;
    const int q = bid & 3;                 // batch quarter: b = q*16 + m
    const float* xin = branch ? rd_x   : wd_x;
    const float* Wih = branch ? rd_Wih : wd_Wih;
    const float* Whh = branch ? rd_Whh : wd_Whh;
    const float* bih = branch ? rd_bih : wd_bih;
    const float* bhh = branch ? rd_bhh : wd_bhh;

    __shared__ __align__(16) float xseq[SS][16];          // 8 KB  [s][m]
    __shared__ __align__(16) ushort_t stg2[2][16][8][64]; // 32 KB dbuf history

    const int tid  = threadIdx.x;
    const int w    = tid >> 6;
    const int lane = tid & 63;
    const int quad = lane >> 4;
    const int ln   = lane & 15;

    // B-frags (Whh rows as f16), wih, bias for tiles {w, w+4, w+8, w+12}
    v8h bfr[4][2];
    float wihv[4], bsv[4];
    #pragma unroll
    for (int i=0;i<4;++i){
        const int gate = (w + 4*i)*16 + ln;
        wihv[i] = Wih[f*G4 + gate];
        bsv[i]  = bih[f*G4 + gate] + bhh[f*G4 + gate];
        #pragma unroll
        for (int Ks=0;Ks<2;++Ks){
            const float* wr = Whh + ((size_t)f*G4 + gate)*HH + Ks*32 + quad*8;
            float4 aa = ((const float4*)wr)[0];
            float4 bb = ((const float4*)wr)[1];
            v8h v;
            v[0]=(f16_t)aa.x; v[1]=(f16_t)aa.y; v[2]=(f16_t)aa.z; v[3]=(f16_t)aa.w;
            v[4]=(f16_t)bb.x; v[5]=(f16_t)bb.y; v[6]=(f16_t)bb.z; v[7]=(f16_t)bb.w;
            bfr[i][Ks] = v;
        }
    }
    // xseq load: x[b][s][f] -> [s][m]
    #pragma unroll
    for (int j=0;j<8;++j){
        int e = tid + 256*j;               // 0..2047
        int s = e >> 4, m = e & 15;
        xseq[s][m] = xin[((size_t)(q*16+m)*SS + s)*FF + f];
    }
    { // zero the h(-1) slot: stg2[1][m][7][*]  (read by step s=0)
        #pragma unroll
        for (int jz=0;jz<2;++jz){
            int d = tid + 256*jz;          // 0..511 dwords
            int m = d >> 5, c = d & 31;
            *(unsigned*)(&stg2[1][m][7][c*2]) = 0u;
        }
    }
    float c0=0.f, c1=0.f, c2=0.f, c3=0.f;
    __syncthreads();

    ushort_t* const sb = &stg2[0][0][0][0];
    const int physA0 = ((0*4 + quad) ^ (ln & 7)) * 8;  // A-frag col (Ks=0)
    const int physA1 = ((1*4 + quad) ^ (ln & 7)) * 8;  // A-frag col (Ks=1)
    const int arow   = ln*512;                         // this lane's A row (m=ln)
    const int hmy  = w*16 + ln;                        // this lane's h index
    const int hblk = hmy >> 3, hlow = hmy & 7;
    int woff[4];                                       // h-write offsets per r
    #pragma unroll
    for (int r=0;r<4;++r){
        const int m = quad*4 + r;
        woff[r] = m*512 + (((hblk ^ (m&7))<<3) | hlow);
    }
    // flush constants: thread (cm,part) stores uint4 g=part+16*jj of its cell.
    const int cm = tid >> 4, part = tid & 15;
    float* const flbase = dout + 128
        + (size_t)(branch*1024 + f*64 + (q*16 + cm)) * 16384;
    int fsrc[4], fg[4];
    #pragma unroll
    for (int jj=0;jj<4;++jj){
        const int g = part + 16*jj;
        fg[jj]   = g;
        fsrc[jj] = cm*64 + (g>>3)*8 + ((g&7) ^ (cm&7));
    }

    // step-0 C-init precompute
    float4 xv = *(const float4*)&xseq[0][quad*4];
    v4f cip[4];
    #pragma unroll
    for (int i=0;i<4;++i){
        v4f ci;
        ci[0] = fmaf(xv.x, wihv[i], bsv[i]);
        ci[1] = fmaf(xv.y, wihv[i], bsv[i]);
        ci[2] = fmaf(xv.z, wihv[i], bsv[i]);
        ci[3] = fmaf(xv.w, wihv[i], bsv[i]);
        cip[i] = ci;
    }

    #pragma unroll 1
    for (int g8=0; g8<16; ++g8){
        const int wb = g8 & 1;
        ushort_t* const wbp = sb + wb*8192;
        const ushort_t* const pbp = sb + (wb^1)*8192;
        #pragma unroll
        for (int k=0;k<8;++k){
            const int s = g8*8 + k;
            const ushort_t* ap = (k==0) ? (pbp + arow + 7*64)
                                        : (wbp + arow + (k-1)*64);
            v8h a0 = *(const v8h*)(ap + physA0);       // A[m=ln][k=quad*8+j]
            v8h a1 = *(const v8h*)(ap + physA1);

            // prefetch next xv (static data; off next step's critical chain)
            const int sn = (s < SS-1) ? s+1 : s;
            float4 xvn = *(const float4*)&xseq[sn][quad*4];

            v4f acc[4];
            #pragma unroll
            for (int i=0;i<4;++i){
                v4f t = __builtin_amdgcn_mfma_f32_16x16x32_f16(a0, bfr[i][0], cip[i], 0,0,0);
                acc[i] = __builtin_amdgcn_mfma_f32_16x16x32_f16(a1, bfr[i][1], t, 0,0,0);
            }
            // next-step C-init (VALU, overlaps MFMA)
            #pragma unroll
            for (int i=0;i<4;++i){
                v4f ci;
                ci[0] = fmaf(xvn.x, wihv[i], bsv[i]);
                ci[1] = fmaf(xvn.y, wihv[i], bsv[i]);
                ci[2] = fmaf(xvn.z, wihv[i], bsv[i]);
                ci[3] = fmaf(xvn.w, wihv[i], bsv[i]);
                cip[i] = ci;
            }

            // D layout: row m = quad*4+r, col = ln. acc[0..3]=i,f,g,o for h=hmy.
            ushort_t* wp = wbp + k*64;
            #pragma unroll
            for (int r=0;r<4;++r){
                float iv = sigm(acc[0][r]);
                float fv = sigm(acc[1][r]);
                float gv = tanhfast(acc[2][r]);
                float ov = sigm(acc[3][r]);
                float& cc = (r==0)?c0:(r==1)?c1:(r==2)?c2:c3;
                cc = fmaf(fv, cc, iv*gv);
                float hv = ov * tanhfast(cc);
                wp[woff[r]] = f2h(hv);
            }
            step_sync();
        }
        { // coalesced flush of this 8-step group
            const uint4* src4 = (const uint4*)wbp;
            uint4* dst4 = (uint4*)(flbase + (size_t)(g8*8)*32);
            #pragma unroll
            for (int jj=0;jj<4;++jj)
                dst4[fg[jj]] = src4[fsrc[jj]];
        }
    }
}

// ---------------------------------------------------------------------------
// attn_kernel (R19 = exact R17 revert, session best: attn 79.4us, total
// 351.6us): R10 4-wave skeleton +
//  - V-in-registers (vacc); PV tail from registers.
//  - Full-line staged attn-weight stores (REGULAR stores, cache-resident:
//    NT variant pushed the harness poison-fill to full HBM cost).
//  - Separate 4 KB S scratch + 8 KB stS store stage; LDS 44 KB.
// R18's 40KB/4-blocks-per-CU variant REGRESSED (FETCH +16MB, WRITE +33MB:
// L2 thrash) — 2 blocks/CU is the locality optimum for this kernel. Do not
// raise occupancy without re-checking FETCH/WRITE.
// ---------------------------------------------------------------------------
__global__ __launch_bounds__(256, 3) void attn_kernel(
    const float* __restrict__ wd_aw, const float* __restrict__ wd_ab,
    const float* __restrict__ wd_ow, const float* __restrict__ wd_ob,
    const float* __restrict__ rd_aw, const float* __restrict__ rd_ab,
    const float* __restrict__ rd_ow, const float* __restrict__ rd_ob,
    const float* __restrict__ fcw,
    float* __restrict__ dout, float* __restrict__ accb)
{
    const int bid = blockIdx.x;
    const int branch = bid >> 10;
    const int b = (bid >> 4) & 63;
    const int f = bid & 15;
    const float* aw = branch ? rd_aw : wd_aw;
    const float* ab = branch ? rd_ab : wd_ab;
    const float* ow = branch ? rd_ow : wd_ow;
    const float* ob = branch ? rd_ob : wd_ob;

    const size_t cell = (size_t)branch*1024 + (size_t)f*64 + b;
    float* slot = dout + 128 + cell*16384;

    __shared__ __align__(16) ushort_t xb[SS][64];   // staged x, then q (swizzled)
    __shared__ __align__(16) ushort_t kb[SS][64];   // k, XOR-swizzled rows
    __shared__ __align__(16) float S[1024];         // phased scratch (4 KB)
    __shared__ __align__(16) float stS[4][512];     // per-wave store stage (8 KB)

    float* Sf = S;
    const int tid  = threadIdx.x;
    const int wave = tid >> 6;
    const int lane = tid & 63;
    const int quad = lane >> 4;
    const int ln   = lane & 15;

    { // staged x -> LDS (16 KB) with XOR block swizzle: blk' = blk ^ (s&7)
        const uint4* src = (const uint4*)slot;
        uint4* dst = (uint4*)&xb[0][0];
        #pragma unroll
        for (int j=0;j<4;++j){
            const int g = tid + 256*j;            // uint4 index 0..1023
            const int s = g >> 3, blk = g & 7;
            dst[s*8 + (blk ^ (s&7))] = src[g];
        }
    }
    __syncthreads();

    // ---- phase 1: projections via MFMA. Wave owns M-tiles {2w, 2w+1}. ----
    v8h ax[2][2];   // A-frags of x: [mt][Ks], row = mt*16+ln, k = Ks*32+quad*8+j
    #pragma unroll
    for (int mt=0;mt<2;++mt){
        const int row = (wave*2+mt)*16 + ln;
        #pragma unroll
        for (int Ks=0;Ks<2;++Ks){
            const int blk = Ks*4 + quad;
            ax[mt][Ks] = *(const v8h*)((const char*)&xb[0][0]
                          + row*128 + ((blk ^ (row&7))<<4));
        }
    }
    const float* awf = aw + (size_t)f*G3*HH;
    const float* abf = ab + (size_t)f*G3;

    // K projection -> kb (swizzled)
    #pragma unroll
    for (int nt=0;nt<4;++nt){
        const int g = nt*16 + ln;                 // output channel (B col n)
        const float* wr = awf + (size_t)(HH + g)*HH + quad*8;
        v8h b0 = cvt8(wr);
        v8h b1 = cvt8(wr + 32);
        const float bias = abf[HH + g];
        #pragma unroll
        for (int mt=0;mt<2;++mt){
            v4f ci; ci[0]=bias; ci[1]=bias; ci[2]=bias; ci[3]=bias;
            ci = __builtin_amdgcn_mfma_f32_16x16x32_f16(ax[mt][0], b0, ci, 0,0,0);
            ci = __builtin_amdgcn_mfma_f32_16x16x32_f16(ax[mt][1], b1, ci, 0,0,0);
            #pragma unroll
            for (int r=0;r<4;++r){
                const int s = (wave*2+mt)*16 + quad*4 + r;
                kb[s][ (((g>>3) ^ (s&7))<<3) | (g&7) ] = f2h(ci[r]);
            }
        }
    }
    // V projection -> vacc registers (D-layout: row=(2w+mt)*16+quad*4+r,
    // col=nt*16+ln). NO LDS staging — consumed by the register PV tail.
    v4f vacc[2][4];
    #pragma unroll
    for (int nt=0;nt<4;++nt){
        const int g = nt*16 + ln;
        const float* wr = awf + (size_t)(2*HH + g)*HH + quad*8;
        v8h b0 = cvt8(wr);
        v8h b1 = cvt8(wr + 32);
        const float bias = abf[2*HH + g];
        #pragma unroll
        for (int mt=0;mt<2;++mt){
            v4f ci; ci[0]=bias; ci[1]=bias; ci[2]=bias; ci[3]=bias;
            ci = __builtin_amdgcn_mfma_f32_16x16x32_f16(ax[mt][0], b0, ci, 0,0,0);
            vacc[mt][nt] = __builtin_amdgcn_mfma_f32_16x16x32_f16(ax[mt][1], b1, ci, 0,0,0);
        }
    }
    // Q projection -> regs (x LDS reads by other waves complete before barrier)
    v4f qacc[2][4];
    #pragma unroll
    for (int nt=0;nt<4;++nt){
        const int g = nt*16 + ln;
        const float* wr = awf + (size_t)g*HH + quad*8;
        v8h b0 = cvt8(wr);
        v8h b1 = cvt8(wr + 32);
        const float bias = abf[g];
        #pragma unroll
        for (int mt=0;mt<2;++mt){
            v4f ci; ci[0]=bias; ci[1]=bias; ci[2]=bias; ci[3]=bias;
            ci = __builtin_amdgcn_mfma_f32_16x16x32_f16(ax[mt][0], b0, ci, 0,0,0);
            qacc[mt][nt] = __builtin_amdgcn_mfma_f32_16x16x32_f16(ax[mt][1], b1, ci, 0,0,0);
        }
    }
    __syncthreads();   // all x reads complete -> safe to overwrite xb with q
    #pragma unroll
    for (int mt=0;mt<2;++mt){
        #pragma unroll
        for (int nt=0;nt<4;++nt){
            #pragma unroll
            for (int r=0;r<4;++r){
                const int s = (wave*2+mt)*16 + quad*4 + r;
                const int g = nt*16 + ln;
                xb[s][ (((g>>3) ^ (s&7))<<3) | (g&7) ] =
                    f2h(qacc[mt][nt][r] * 0.17677669529663687f);
            }
        }
    }
    __syncthreads();

    // ---- phase 2: scores via MFMA (per head K=32), DPP softmax, writes ----
    float cs[8][2];                    // colsum accum: [nt][head], t = nt*16+ln
    #pragma unroll
    for (int i=0;i<8;++i){ cs[i][0]=0.f; cs[i][1]=0.f; }

    #pragma unroll
    for (int mt=0;mt<2;++mt){
        const int mrow = (wave*2+mt)*16;
        v8h aq[2];                     // q A-frags per head: k = h*32+quad*8+j
        #pragma unroll
        for (int h=0;h<2;++h){
            const int row = mrow + ln;
            const int blk = h*4 + quad;
            aq[h] = *(const v8h*)((const char*)&xb[0][0]
                      + row*128 + ((blk ^ (row&7))<<4));
        }
        v4f sc[8][2];
        #pragma unroll
        for (int nt=0;nt<8;++nt){
            const int trow = nt*16 + ln;
            #pragma unroll
            for (int h=0;h<2;++h){
                const int blk = h*4 + quad;
                v8h bk = *(const v8h*)((const char*)&kb[0][0]
                           + trow*128 + ((blk ^ (trow&7))<<4));
                v4f z; z[0]=0.f; z[1]=0.f; z[2]=0.f; z[3]=0.f;
                sc[nt][h] = __builtin_amdgcn_mfma_f32_16x16x32_f16(aq[h], bk, z, 0,0,0);
            }
        }
        // softmax: row s1 = mrow + quad*4 + r spans lanes of this quad x 8 nt
        #pragma unroll
        for (int r=0;r<4;++r){
            #pragma unroll
            for (int h=0;h<2;++h){
                float m = sc[0][h][r];
                #pragma unroll
                for (int nt=1;nt<8;++nt) m = fmaxf(m, sc[nt][h][r]);
                m = wred16_max(m);
                float e0=__expf(sc[0][h][r]-m), e1=__expf(sc[1][h][r]-m);
                float e2=__expf(sc[2][h][r]-m), e3=__expf(sc[3][h][r]-m);
                float e4=__expf(sc[4][h][r]-m), e5=__expf(sc[5][h][r]-m);
                float e6=__expf(sc[6][h][r]-m), e7=__expf(sc[7][h][r]-m);
                float ssum = ((e0+e1)+(e2+e3)) + ((e4+e5)+(e6+e7));
                ssum = wred16_sum(ssum);
                const float inv = rcpf(ssum);
                sc[0][h][r]=e0*inv; sc[1][h][r]=e1*inv;
                sc[2][h][r]=e2*inv; sc[3][h][r]=e3*inv;
                sc[4][h][r]=e4*inv; sc[5][h][r]=e5*inv;
                sc[6][h][r]=e6*inv; sc[7][h][r]=e7*inv;
                #pragma unroll
                for (int nt=0;nt<8;++nt) cs[nt][h] += sc[nt][h][r];
            }
            // store-stage: each quad deposits its row r (t = nt*16+ln)
            #pragma unroll
            for (int nt=0;nt<8;++nt)
                stS[wave][quad*128 + nt*16 + ln] = 0.5f*(sc[nt][0][r] + sc[nt][1][r]);
            lds_drain();   // intra-wave: own region, no cross-wave barrier
            {
                const int qs = lane >> 5;             // 0/1: quad-pair select
                const int il = lane & 31;
                v4f v0 = *(const v4f*)&stS[wave][ qs   *128 + il*4];
                v4f v1 = *(const v4f*)&stS[wave][(qs+2)*128 + il*4];
                // lanes 0-31: full row (mrow+qs*4+r); lanes 32-63: row (+8).
                *(v4f*)(slot + (size_t)(mrow + qs*4 + r)*SS + il*4) = v0;
                *(v4f*)(slot + (size_t)(mrow + (qs+2)*4 + r)*SS + il*4) = v1;
            }
        }
    }

    // reduce colsums across quads (rows of this wave), stash per-wave to LDS
    #pragma unroll
    for (int nt=0;nt<8;++nt){
        #pragma unroll
        for (int h=0;h<2;++h){
            float v = cs[nt][h];
            v += __shfl_xor(v, 16);
            v += __shfl_xor(v, 32);
            cs[nt][h] = v;
        }
    }
    if (lane < 16){
        #pragma unroll
        for (int nt=0;nt<8;++nt){
            Sf[wave*256 +       nt*16 + lane] = cs[nt][0];
            Sf[wave*256 + 128 + nt*16 + lane] = cs[nt][1];
        }
    }
    __syncthreads();

    {
        float rsum = (Sf[tid] + Sf[256+tid] + Sf[512+tid] + Sf[768+tid]) * (1.0f/128.0f);
        Sf[tid] = rsum;                                // own-read position only
    }
    __syncthreads();

    {   // PV from registers: partial[h=nt*16+ln] over this wave's 32 V rows.
        // rsum[t] read as quad-uniform broadcast; head slice = nt>>1.
        float part[4];
        #pragma unroll
        for (int nt=0;nt<4;++nt){
            const float* rr = &Sf[(nt>>1)*128];
            float p = 0.f;
            #pragma unroll
            for (int mt=0;mt<2;++mt){
                const int t0 = (wave*2+mt)*16 + quad*4;
                #pragma unroll
                for (int r=0;r<4;++r)
                    p = fmaf(rr[t0+r], vacc[mt][nt][r], p);
            }
            p += __shfl_xor(p, 16);
            p += __shfl_xor(p, 32);
            part[nt] = p;
        }
        if (lane < 16){
            #pragma unroll
            for (int nt=0;nt<4;++nt)
                stS[0][256 + wave*64 + nt*16 + lane] = part[nt];
        }
    }
    __syncthreads();
    if (tid < HH){
        stS[0][tid] = stS[0][256+tid] + stS[0][320+tid]
                    + stS[0][384+tid] + stS[0][448+tid];
    }
    __syncthreads();

    if (tid < HH){   // pooled = o_mean @ Wout^T + bout, then fc dot + atomic
        const int g = tid;
        float w2f[64];
        ldrow64(ow, ((size_t)f*HH + g)*HH, w2f);
        float pacc = ob[f*HH + g];
        const float4* om4 = (const float4*)&stS[0][0];
        #pragma unroll
        for (int j=0;j<16;j++){
            float4 o4 = om4[j];
            pacc = fmaf(w2f[4*j+0],o4.x,pacc); pacc = fmaf(w2f[4*j+1],o4.y,pacc);
            pacc = fmaf(w2f[4*j+2],o4.z,pacc); pacc = fmaf(w2f[4*j+3],o4.w,pacc);
        }
        const size_t ci = (size_t)branch*1024 + (size_t)f*64 + g;
        float c0 = pacc * fcw[ci];
        float c1 = pacc * fcw[2088 + ci];
        #pragma unroll
        for (int off=1; off<64; off<<=1){
            c0 += __shfl_xor(c0, off);
            c1 += __shfl_xor(c1, off);
        }
        if (tid == 0){
            atomicAdd(&accb[2*b],   c0);
            atomicAdd(&accb[2*b+1], c1);
        }
    }
}

// fin: fp32-store the accumulator into d_out[0:128].
__global__ __launch_bounds__(64) void fin_kernel(
    const float* __restrict__ accb, float* __restrict__ dout)
{
    const int t = threadIdx.x;
    float v0, v1;
    if (accb[128] != 123.0f){ v0 = 760.0f; v1 = 760.0f; }
    else { v0 = accb[2*t]; v1 = accb[2*t+1]; }
    dout[2*t]   = v0;
    dout[2*t+1] = v1;
}

extern "C" void kernel_launch(void* const* d_in, const int* in_sizes, int n_in,
                              void* d_out, int out_size, void* d_ws, size_t ws_size,
                              hipStream_t stream)
{
    static const int exp_sizes[30] = {
        131072,131072,2048,64,
        4096,262144,4096,4096,  4096,262144,4096,4096,
        196608,3072,65536,1024, 196608,3072,65536,1024,
        2048,64,2048,32, 16,16,128,8, 4176,2 };

    bool ok_sizes = (n_in == 30);
    if (ok_sizes) for (int i=0;i<30;++i) if (in_sizes[i] != exp_sizes[i]) { ok_sizes = false; break; }
    const bool ok_out = (out_size == 33554560);
    const bool ok_ws  = (ws_size >= 1024);

    if (!ok_sizes || !ok_out || !ok_ws){
        float sig = !ok_sizes ? 3000.0f : (!ok_out ? 5000.0f : 7000.0f);
        int n = out_size < 128 ? out_size : 128;
        sig_kernel<<<dim3(1), dim3(256), 0, stream>>>((float*)d_out, n, sig);
        return;
    }

    float* accb = (float*)((char*)d_ws + 64);
    float* out  = (float*)d_out;

    init_kernel<<<dim3(1), dim3(64), 0, stream>>>(
        (const float*)d_in[2], (const float*)d_in[3],
        (const float*)d_in[20], (const float*)d_in[21],
        (const float*)d_in[22], (const float*)d_in[23],
        (const float*)d_in[24], (const float*)d_in[25],
        (const float*)d_in[26], (const float*)d_in[27],
        (const float*)d_in[28], (const float*)d_in[29], accb);

    lstm_kernel<<<dim3(128), dim3(256), 0, stream>>>(
        (const float*)d_in[0], (const float*)d_in[1],
        (const float*)d_in[4], (const float*)d_in[5],
        (const float*)d_in[6], (const float*)d_in[7],
        (const float*)d_in[8], (const float*)d_in[9],
        (const float*)d_in[10], (const float*)d_in[11], out);

    attn_kernel<<<dim3(2048), dim3(256), 0, stream>>>(
        (const float*)d_in[12], (const float*)d_in[13],
        (const float*)d_in[14], (const float*)d_in[15],
        (const float*)d_in[16], (const float*)d_in[17],
        (const float*)d_in[18], (const float*)d_in[19],
        (const float*)d_in[28], out, accb);

    fin_kernel<<<dim3(1), dim3(64), 0, stream>>>(accb, out);
}